// Round 11
// baseline (117.413 us; speedup 1.0000x reference)
//
#include <hip/hip_runtime.h>
#include <stdint.h>

typedef __attribute__((ext_vector_type(8))) short short8;
typedef __attribute__((ext_vector_type(4))) float f32x4;
typedef __attribute__((ext_vector_type(2))) _Float16 h2;
typedef __attribute__((ext_vector_type(8))) _Float16 half8;

#define QSCALE 21.1666667f   /* 127/6 : q,k quantize */
#define SCONST 9.86413e-5f   /* (6/127)^2 / sqrt(512) : score dequant */

static __device__ __forceinline__ unsigned short f2bf(float f) {
  unsigned int u = __float_as_uint(f);
  u += 0x7FFFu + ((u >> 16) & 1u);
  return (unsigned short)(u >> 16);
}
static __device__ __forceinline__ float bf2f(unsigned short h) {
  return __uint_as_float(((unsigned int)h) << 16);
}
static __device__ __forceinline__ unsigned short f2h(float f) {
  _Float16 h = (_Float16)f;
  return __builtin_bit_cast(unsigned short, h);
}
static __device__ __forceinline__ float h2f(unsigned short h) {
  return (float)__builtin_bit_cast(_Float16, h);
}
static __device__ __forceinline__ signed char q8(float v) {
  float sv = fminf(fmaxf(v * QSCALE, -127.f), 127.f);
  return (signed char)(int)rintf(sv);
}
// LLVM pattern-matches this to v_cvt_f32_ubyteN
static __device__ __forceinline__ float ub(unsigned int x, int n) {
  return (float)((x >> (8 * n)) & 0xffu);
}

#define GLD16(gp, lp) __builtin_amdgcn_global_load_lds( \
    (__attribute__((address_space(1))) void*)(gp), \
    (__attribute__((address_space(3))) void*)(lp), 16, 0, 0)

// --------- fused prep: adj-mask gather | x->f16 | all weight transposes ----
__global__ __launch_bounds__(256) void k_prep(
    const float* __restrict__ adj, const int* __restrict__ inxs,
    float* __restrict__ maskb, const float* __restrict__ x,
    unsigned short* __restrict__ xb,
    const float* __restrict__ Wq, const float* __restrict__ Wk,
    const float* __restrict__ Wv, const float* __restrict__ Wo,
    const float* __restrict__ W1, const float* __restrict__ W2,
    unsigned short* __restrict__ wqkvt, unsigned short* __restrict__ wot,
    unsigned short* __restrict__ w1t, unsigned short* __restrict__ w2t) {
  __shared__ float tile[32][33];
  const int bid = blockIdx.x;
  const int t = threadIdx.x;
  if (bid < 1024) {
    const int xcd = bid & 7;
    const int bb = xcd >> 1;
    const int s = ((bid >> 3) << 1) | (xcd & 1);
    const long row = ((long)bb << 11) | ((long)s << 3) | (t >> 5);
    const int kk = t & 31;
    const int idx = inxs[row * 32 + kk];
    const float a = adj[row * 2048 + idx];
    maskb[row * 32 + kk] = a > 0.f ? 0.f : -1e22f;
    return;
  }
  if (bid < 3072) {
    const int lb = bid - 1024;
    const int xcd = lb & 7;
    const int bb = xcd >> 1;
    const int s = ((lb >> 3) << 1) | (xcd & 1);
    const long row = ((long)bb << 11) | ((long)s << 2) | (t >> 6);
    const int lane = t & 63;
    const float4* p = (const float4*)(x + row * 512 + lane * 8);
    float4 a = p[0], b = p[1];
    short8 v;
    v[0] = (short)f2h(a.x); v[1] = (short)f2h(a.y);
    v[2] = (short)f2h(a.z); v[3] = (short)f2h(a.w);
    v[4] = (short)f2h(b.x); v[5] = (short)f2h(b.y);
    v[6] = (short)f2h(b.z); v[7] = (short)f2h(b.w);
    *(short8*)(xb + row * 512 + lane * 8) = v;
    return;
  }
  const int lb = bid - 3072;
  const float* src;
  unsigned short* dst;
  int R, C, f16, local;
  if (lb < 768) {
    const int m = lb >> 8;
    src = m == 0 ? Wq : (m == 1 ? Wk : Wv);
    dst = wqkvt + (long)m * 512 * 512;
    R = 512; C = 512; f16 = 1; local = lb & 255;
  } else if (lb < 1024) {
    src = Wo; dst = wot; R = 512; C = 512; f16 = 0; local = lb - 768;
  } else if (lb < 1408) {
    src = W1; dst = w1t; R = 512; C = 768; f16 = 0; local = lb - 1024;
  } else {
    src = W2; dst = w2t; R = 768; C = 512; f16 = 0; local = lb - 1408;
  }
  const int ntx = C >> 5;
  const int c0 = (local % ntx) << 5;
  const int r0 = (local / ntx) << 5;
  const int tx = t & 31, ty = t >> 5;
#pragma unroll
  for (int i = 0; i < 4; i++)
    tile[ty + i * 8][tx] = src[(long)(r0 + ty + i * 8) * C + c0 + tx];
  __syncthreads();
#pragma unroll
  for (int i = 0; i < 4; i++) {
    float v = tile[tx][ty + i * 8];
    dst[(long)(c0 + ty + i * 8) * R + r0 + tx] = f16 ? f2h(v) : f2bf(v);
  }
}

// ---- G1: f16 MFMA GEMM 128x128, BK=64, dbuf, epilogue -> int8 q,k | f16 v --
__global__ __launch_bounds__(256) void k_gemm_qkv(
    const unsigned short* __restrict__ A, const unsigned short* __restrict__ Bt,
    const float* __restrict__ bq, const float* __restrict__ bk,
    const float* __restrict__ bv, signed char* __restrict__ qk8,
    unsigned short* __restrict__ vh) {
  const int K = 512;
  __shared__ unsigned short As[2][128 * 64];
  __shared__ unsigned short Bs[2][128 * 64];
  const int t = threadIdx.x;
  const int lane = t & 63;
  const int w = t >> 6;
  const int wr = w >> 1, wc = w & 1;
  const int lin = blockIdx.x;
  const int xcd = lin & 7;
  const int bb = xcd >> 1;
  const int s = ((lin >> 3) << 1) | (xcd & 1);  // 0..191
  const int m0 = (bb * 16 + s / 12) * 128;
  const int n0 = (s % 12) * 128;

  f32x4 acc[4][4];
#pragma unroll
  for (int mi = 0; mi < 4; mi++)
#pragma unroll
    for (int ni = 0; ni < 4; ni++) {
      f32x4 z = {0.f, 0.f, 0.f, 0.f};
      acc[mi][ni] = z;
    }

  auto stage = [&](int buf, int k0) {
#pragma unroll
    for (int i = 0; i < 4; i++) {
      const int c = t + i * 256;
      const int r = c >> 3, j = c & 7;
      GLD16(A + (long)(m0 + r) * K + k0 + ((j ^ (r & 7)) << 3), &As[buf][c * 8]);
    }
#pragma unroll
    for (int i = 0; i < 4; i++) {
      const int c = t + i * 256;
      const int r = c >> 3, j = c & 7;
      GLD16(Bt + (long)(n0 + r) * K + k0 + ((j ^ (r & 7)) << 3), &Bs[buf][c * 8]);
    }
  };

  const int nt = K >> 6;  // 8
  stage(0, 0);
  for (int tt = 0; tt < nt; ++tt) {
    const int cur = tt & 1;
    if (tt + 1 < nt) {
      stage(cur ^ 1, (tt + 1) << 6);
      asm volatile("s_waitcnt vmcnt(8)" ::: "memory");
    } else {
      asm volatile("s_waitcnt vmcnt(0)" ::: "memory");
    }
    __builtin_amdgcn_s_barrier();

#pragma unroll
    for (int kk = 0; kk < 2; kk++) {
      short8 af[4], bf[4];
#pragma unroll
      for (int mi = 0; mi < 4; mi++) {
        const int r = wr * 64 + mi * 16 + (lane & 15);
        const int jj = (kk << 2) + (lane >> 4);
        af[mi] = *(const short8*)&As[cur][r * 64 + ((jj ^ (r & 7)) << 3)];
      }
#pragma unroll
      for (int ni = 0; ni < 4; ni++) {
        const int r = wc * 64 + ni * 16 + (lane & 15);
        const int jj = (kk << 2) + (lane >> 4);
        bf[ni] = *(const short8*)&Bs[cur][r * 64 + ((jj ^ (r & 7)) << 3)];
      }
#pragma unroll
      for (int mi = 0; mi < 4; mi++)
#pragma unroll
        for (int ni = 0; ni < 4; ni++)
          acc[mi][ni] = __builtin_amdgcn_mfma_f32_16x16x32_f16(
              __builtin_bit_cast(half8, af[mi]), __builtin_bit_cast(half8, bf[ni]),
              acc[mi][ni], 0, 0, 0);
    }
    asm volatile("s_waitcnt lgkmcnt(0)" ::: "memory");
    __builtin_amdgcn_s_barrier();
  }

  const int lr = (lane >> 4) * 4;
  const int lc = lane & 15;
  if (n0 < 1024) {
#pragma unroll
    for (int mi = 0; mi < 4; mi++) {
#pragma unroll
      for (int ni = 0; ni < 4; ni++) {
        const int col = n0 + wc * 64 + ni * 16 + lc;
        const float bvv = col < 512 ? bq[col] : bk[col - 512];
#pragma unroll
        for (int r = 0; r < 4; r++) {
          const int row = m0 + wr * 64 + mi * 16 + lr + r;
          qk8[(long)row * 1024 + col] = q8(acc[mi][ni][r] + bvv);
        }
      }
    }
  } else {
#pragma unroll
    for (int mi = 0; mi < 4; mi++) {
#pragma unroll
      for (int ni = 0; ni < 4; ni++) {
        const int col = n0 + wc * 64 + ni * 16 + lc;
        const float bvv = bv[col - 1024];
#pragma unroll
        for (int r = 0; r < 4; r++) {
          const int row = m0 + wr * 64 + mi * 16 + lr + r;
          vh[(long)row * 512 + (col - 1024)] = f2h(acc[mi][ni][r] + bvv);
        }
      }
    }
  }
}

// ------ quantize v rows: uint8 (bias 128) + per-row f32 scale --------------
__global__ __launch_bounds__(256) void k_qv(const unsigned short* __restrict__ vh,
                                            unsigned char* __restrict__ v8,
                                            float* __restrict__ vs) {
  const int bid = blockIdx.x;
  const int xcd = bid & 7;
  const int bb = xcd >> 1;
  const int s0 = ((bid >> 3) << 1) | (xcd & 1);
  const long row = ((long)bb << 11) | ((long)s0 << 2) | (threadIdx.x >> 6);
  const int lane = threadIdx.x & 63;
  const unsigned short* vp = vh + row * 512 + lane * 8;
  float vf[8];
#pragma unroll
  for (int j = 0; j < 8; j++) vf[j] = h2f(vp[j]);
  float mx = 0.f;
#pragma unroll
  for (int j = 0; j < 8; j++) mx = fmaxf(mx, fabsf(vf[j]));
#pragma unroll
  for (int d = 1; d <= 32; d <<= 1) mx = fmaxf(mx, __shfl_xor(mx, d, 64));
  mx = fmaxf(mx, 1e-8f);
  const float sc = mx * (1.f / 127.f);
  const float isc = 127.f / mx;
  unsigned int w0 = 0, w1 = 0;
#pragma unroll
  for (int j = 0; j < 4; j++) {
    unsigned int u = (unsigned int)(int)rintf(fminf(fmaxf(vf[j] * isc + 128.f, 0.f), 255.f));
    w0 |= (u & 255u) << (8 * j);
  }
#pragma unroll
  for (int j = 0; j < 4; j++) {
    unsigned int u = (unsigned int)(int)rintf(fminf(fmaxf(vf[4 + j] * isc + 128.f, 0.f), 255.f));
    w1 |= (u & 255u) << (8 * j);
  }
  uint2 pw = {w0, w1};
  *(uint2*)(v8 + row * 512 + lane * 8) = pw;
  if (lane == 0) vs[row] = sc;
}

// ------- bf16 MFMA GEMM, 128x128 tile, BK=64, dbuf + counted vmcnt --------
template <int EPI>
__global__ __launch_bounds__(256) void k_gemm(const unsigned short* __restrict__ A,
                                              const unsigned short* __restrict__ Bt,
                                              const float* __restrict__ bias,
                                              unsigned short* __restrict__ C,
                                              int M, int N, int K) {
  __shared__ unsigned short As[2][128 * 64];
  __shared__ unsigned short Bs[2][128 * 64];
  const int t = threadIdx.x;
  const int lane = t & 63;
  const int w = t >> 6;
  const int wr = w >> 1, wc = w & 1;
  const int lin = blockIdx.x;
  const int xcd = lin & 7;
  const int bb = xcd >> 1;
  const int nx = N >> 7;
  const int s = ((lin >> 3) << 1) | (xcd & 1);
  const int m0 = (bb * 16 + s / nx) * 128;
  const int n0 = (s % nx) * 128;

  f32x4 acc[4][4];
#pragma unroll
  for (int mi = 0; mi < 4; mi++)
#pragma unroll
    for (int ni = 0; ni < 4; ni++) {
      f32x4 z = {0.f, 0.f, 0.f, 0.f};
      acc[mi][ni] = z;
    }

  auto stage = [&](int buf, int k0) {
#pragma unroll
    for (int i = 0; i < 4; i++) {
      const int c = t + i * 256;
      const int r = c >> 3, j = c & 7;
      GLD16(A + (long)(m0 + r) * K + k0 + ((j ^ (r & 7)) << 3), &As[buf][c * 8]);
    }
#pragma unroll
    for (int i = 0; i < 4; i++) {
      const int c = t + i * 256;
      const int r = c >> 3, j = c & 7;
      GLD16(Bt + (long)(n0 + r) * K + k0 + ((j ^ (r & 7)) << 3), &Bs[buf][c * 8]);
    }
  };

  const int nt = K >> 6;
  stage(0, 0);
  for (int tt = 0; tt < nt; ++tt) {
    const int cur = tt & 1;
    if (tt + 1 < nt) {
      stage(cur ^ 1, (tt + 1) << 6);
      asm volatile("s_waitcnt vmcnt(8)" ::: "memory");
    } else {
      asm volatile("s_waitcnt vmcnt(0)" ::: "memory");
    }
    __builtin_amdgcn_s_barrier();

#pragma unroll
    for (int kk = 0; kk < 2; kk++) {
      short8 af[4], bf[4];
#pragma unroll
      for (int mi = 0; mi < 4; mi++) {
        const int r = wr * 64 + mi * 16 + (lane & 15);
        const int jj = (kk << 2) + (lane >> 4);
        af[mi] = *(const short8*)&As[cur][r * 64 + ((jj ^ (r & 7)) << 3)];
      }
#pragma unroll
      for (int ni = 0; ni < 4; ni++) {
        const int r = wc * 64 + ni * 16 + (lane & 15);
        const int jj = (kk << 2) + (lane >> 4);
        bf[ni] = *(const short8*)&Bs[cur][r * 64 + ((jj ^ (r & 7)) << 3)];
      }
#pragma unroll
      for (int mi = 0; mi < 4; mi++)
#pragma unroll
        for (int ni = 0; ni < 4; ni++)
          acc[mi][ni] = __builtin_amdgcn_mfma_f32_16x16x32_bf16(af[mi], bf[ni], acc[mi][ni], 0, 0, 0);
    }
    asm volatile("s_waitcnt lgkmcnt(0)" ::: "memory");
    __builtin_amdgcn_s_barrier();
  }

  const int lr = (lane >> 4) * 4;
  const int lc = lane & 15;
#pragma unroll
  for (int mi = 0; mi < 4; mi++) {
#pragma unroll
    for (int ni = 0; ni < 4; ni++) {
      const int col = n0 + wc * 64 + ni * 16 + lc;
      const float bvv = bias[col];
#pragma unroll
      for (int r = 0; r < 4; r++) {
        const int row = m0 + wr * 64 + mi * 16 + lr + r;
        float v = acc[mi][ni][r] + bvv;
        if (EPI == 1) v = fmaxf(v, 0.f);
        C[(long)row * N + col] = f2bf(v);
      }
    }
  }
}

// -------- attention: int8 q,k scores (sdot4), uint8 per-row-scaled v PV ----
__global__ __launch_bounds__(256, 8) void k_attn(const signed char* __restrict__ qk8,
                                                 const unsigned char* __restrict__ v8,
                                                 const float* __restrict__ vs,
                                                 const float* __restrict__ maskb,
                                                 const int* __restrict__ inxs,
                                                 unsigned short* __restrict__ att) {
  const int t = threadIdx.x;
  const int lane = t & 63;
  const int w = t >> 6;
  const int bid = blockIdx.x;
  const int xcd = bid & 7;
  const int b = xcd >> 1;
  const int sub = ((bid >> 3) << 1) | (xcd & 1);
  const int row = (b << 11) | (sub << 2) | w;
  const long base = (long)b * 2048;
  const int g = lane >> 4;
  const int li = lane & 15;
  const int kk = lane & 31;

  const int* ix = inxs + (long)row * 32;
  const int ixv = ix[kk];
  const float mval = maskb[(long)row * 32 + kk];
  const float sv = vs[base + ixv];

  const uint2* qp = (const uint2*)(qk8 + (long)row * 1024);
  uint2 qc[4];
#pragma unroll
  for (int c = 0; c < 4; c++) qc[c] = qp[li + c * 16];

  // scores: 8 rounds x 4 concurrent neighbors, int8 dot via sdot4
  float scr[8];
#pragma unroll
  for (int r = 0; r < 8; r++) {
    const int nb = __shfl(ixv, r * 4 + g, 64);
    const uint2* kp = (const uint2*)(qk8 + (base + nb) * 1024 + 512);
    int di = 0;
#pragma unroll
    for (int c = 0; c < 4; c++) {
      uint2 kc = kp[li + c * 16];
      di = __builtin_amdgcn_sdot4((int)kc.x, (int)qc[c].x, di, false);
      di = __builtin_amdgcn_sdot4((int)kc.y, (int)qc[c].y, di, false);
    }
#pragma unroll
    for (int m = 1; m <= 8; m <<= 1) di += __shfl_xor(di, m, 64);
    scr[r] = (float)di;
  }

  // redistribute: lane kk takes scr[kk>>2] from lane (kk&3)*16
  const int srcl = (kk & 3) << 4;
  float s = __shfl(scr[0], srcl, 64);
#pragma unroll
  for (int r = 1; r < 8; r++) {
    const float tr = __shfl(scr[r], srcl, 64);
    s = ((kk >> 2) == r) ? tr : s;
  }
  s = s * SCONST + mval;

  // softmax across 32 owned scores
  float mx = s;
#pragma unroll
  for (int d = 1; d <= 16; d <<= 1) mx = fmaxf(mx, __shfl_xor(mx, d, 64));
  const float e = __expf(s - mx);
  float ts = e;
#pragma unroll
  for (int d = 1; d <= 16; d <<= 1) ts += __shfl_xor(ts, d, 64);
  const float inv = 1.f / ts;

  // per-neighbor weight folds the v row-scale; Σw for the bias-128 correction
  const float wgt = e * sv;
  float sw = wgt;
#pragma unroll
  for (int d = 1; d <= 16; d <<= 1) sw += __shfl_xor(sw, d, 64);

  // PV: 32 neighbors, uint8 v rows (8 B/lane), byte-extract unpack
  float o[8] = {0, 0, 0, 0, 0, 0, 0, 0};
#pragma unroll
  for (int p = 0; p < 32; p++) {
    const int un = __shfl(ixv, p, 64);
    const float wn = __shfl(wgt, p, 64);
    const uint2 vv = *(const uint2*)(v8 + (base + un) * 512 + lane * 8);
    o[0] += wn * ub(vv.x, 0);
    o[1] += wn * ub(vv.x, 1);
    o[2] += wn * ub(vv.x, 2);
    o[3] += wn * ub(vv.x, 3);
    o[4] += wn * ub(vv.y, 0);
    o[5] += wn * ub(vv.y, 1);
    o[6] += wn * ub(vv.y, 2);
    o[7] += wn * ub(vv.y, 3);
  }

  short8 ov;
#pragma unroll
  for (int j = 0; j < 8; j++) ov[j] = (short)f2bf((o[j] - 128.f * sw) * inv);
  *(short8*)(att + (long)row * 512 + lane * 8) = ov;
}

// ---------------- LN1: y = LN(x_f32 + o_bf16) * g + beta, out bf16 --------
__global__ __launch_bounds__(256) void k_ln1(const float* __restrict__ x,
                                             const unsigned short* __restrict__ o,
                                             const float* __restrict__ g,
                                             const float* __restrict__ beta,
                                             unsigned short* __restrict__ y) {
  const int lane = threadIdx.x & 63;
  const int w = threadIdx.x >> 6;
  const int bid = blockIdx.x;
  const int xcd = bid & 7;
  const int bb = xcd >> 1;
  const int s0 = ((bid >> 3) << 1) | (xcd & 1);
  const long row = ((long)bb << 11) | ((long)s0 << 2) | w;
  const float4* xp = (const float4*)(x + row * 512 + lane * 8);
  float4 x0 = xp[0], x1 = xp[1];
  short8 ov = *(const short8*)(o + row * 512 + lane * 8);
  float tv[8] = {x0.x, x0.y, x0.z, x0.w, x1.x, x1.y, x1.z, x1.w};
  float s = 0.f, s2 = 0.f;
#pragma unroll
  for (int j = 0; j < 8; j++) {
    tv[j] += bf2f((unsigned short)ov[j]);
    s += tv[j];
    s2 += tv[j] * tv[j];
  }
#pragma unroll
  for (int m = 32; m >= 1; m >>= 1) {
    s += __shfl_xor(s, m, 64);
    s2 += __shfl_xor(s2, m, 64);
  }
  const float mean = s * (1.f / 512.f);
  const float var = s2 * (1.f / 512.f) - mean * mean;
  const float r = rsqrtf(var + 1e-5f);
  const float4* gp = (const float4*)(g + lane * 8);
  const float4* bp = (const float4*)(beta + lane * 8);
  float4 g0 = gp[0], g1v = gp[1], b0 = bp[0], b1 = bp[1];
  float gg[8] = {g0.x, g0.y, g0.z, g0.w, g1v.x, g1v.y, g1v.z, g1v.w};
  float bb2[8] = {b0.x, b0.y, b0.z, b0.w, b1.x, b1.y, b1.z, b1.w};
  short8 yv;
#pragma unroll
  for (int j = 0; j < 8; j++) yv[j] = (short)f2bf((tv[j] - mean) * r * gg[j] + bb2[j]);
  *(short8*)(y + row * 512 + lane * 8) = yv;
}

// ---------------- LN2: out_f32 = LN(y_bf16 + f_bf16) * g + beta -----------
__global__ __launch_bounds__(256) void k_ln2(const unsigned short* __restrict__ y,
                                             const unsigned short* __restrict__ f,
                                             const float* __restrict__ g,
                                             const float* __restrict__ beta,
                                             float* __restrict__ out) {
  const int lane = threadIdx.x & 63;
  const int w = threadIdx.x >> 6;
  const int bid = blockIdx.x;
  const int xcd = bid & 7;
  const int bb = xcd >> 1;
  const int s0 = ((bid >> 3) << 1) | (xcd & 1);
  const long row = ((long)bb << 11) | ((long)s0 << 2) | w;
  short8 yv = *(const short8*)(y + row * 512 + lane * 8);
  short8 fv = *(const short8*)(f + row * 512 + lane * 8);
  float tv[8];
  float s = 0.f, s2 = 0.f;
#pragma unroll
  for (int j = 0; j < 8; j++) {
    tv[j] = bf2f((unsigned short)yv[j]) + bf2f((unsigned short)fv[j]);
    s += tv[j];
    s2 += tv[j] * tv[j];
  }
#pragma unroll
  for (int m = 32; m >= 1; m >>= 1) {
    s += __shfl_xor(s, m, 64);
    s2 += __shfl_xor(s2, m, 64);
  }
  const float mean = s * (1.f / 512.f);
  const float var = s2 * (1.f / 512.f) - mean * mean;
  const float r = rsqrtf(var + 1e-5f);
  const float4* gp = (const float4*)(g + lane * 8);
  const float4* bp = (const float4*)(beta + lane * 8);
  float4 g0 = gp[0], g1v = gp[1], b0 = bp[0], b1 = bp[1];
  float gg[8] = {g0.x, g0.y, g0.z, g0.w, g1v.x, g1v.y, g1v.z, g1v.w};
  float bb2[8] = {b0.x, b0.y, b0.z, b0.w, b1.x, b1.y, b1.z, b1.w};
  float ovv[8];
#pragma unroll
  for (int j = 0; j < 8; j++) ovv[j] = (tv[j] - mean) * r * gg[j] + bb2[j];
  float4* op = (float4*)(out + row * 512 + lane * 8);
  float4 o0 = {ovv[0], ovv[1], ovv[2], ovv[3]};
  float4 o1 = {ovv[4], ovv[5], ovv[6], ovv[7]};
  op[0] = o0;
  op[1] = o1;
}

extern "C" void kernel_launch(void* const* d_in, const int* in_sizes, int n_in,
                              void* d_out, int out_size, void* d_ws, size_t ws_size,
                              hipStream_t stream) {
  const float* x   = (const float*)d_in[0];
  const float* adj = (const float*)d_in[1];
  const int*   inx = (const int*)d_in[2];
  const float* Wq  = (const float*)d_in[3];
  const float* bq  = (const float*)d_in[4];
  const float* Wk  = (const float*)d_in[5];
  const float* bk  = (const float*)d_in[6];
  const float* Wv  = (const float*)d_in[7];
  const float* bv  = (const float*)d_in[8];
  const float* Wo  = (const float*)d_in[9];
  const float* bo  = (const float*)d_in[10];
  const float* g1  = (const float*)d_in[11];
  const float* be1 = (const float*)d_in[12];
  const float* W1  = (const float*)d_in[13];
  const float* bf1 = (const float*)d_in[14];
  const float* W2  = (const float*)d_in[15];
  const float* bf2 = (const float*)d_in[16];
  const float* g2  = (const float*)d_in[17];
  const float* be2 = (const float*)d_in[18];

  // workspace (short units). Aliases (stream-ordered safe):
  // att<-xb (dead after G1); h<-qk8+vh (qk8 dead after attn, vh dead after k_qv);
  // f<-oproj (dead after LN1).
  unsigned short* xb    = (unsigned short*)d_ws;            // 4194304 (x f16)
  unsigned short* wqkvt = xb + 4194304;                     // 786432
  unsigned short* wot   = wqkvt + 786432;                   // 262144
  unsigned short* w1t   = wot + 262144;                     // 393216
  unsigned short* w2t   = w1t + 393216;                     // 393216
  signed char*    qk8   = (signed char*)(w2t + 393216);     // 8 MB
  unsigned short* vh    = (unsigned short*)(qk8 + 8388608); // 4194304 (v f16)
  unsigned short* oproj = vh + 4194304;                     // 4194304
  unsigned short* y     = oproj + 4194304;                  // 4194304
  float*          maskb = (float*)(y + 4194304);            // 1 MB
  unsigned char*  v8    = (unsigned char*)(maskb + 262144); // 4 MB
  float*          vs    = (float*)(v8 + 4194304);           // 32 KB
  unsigned short* att   = xb;
  unsigned short* h     = (unsigned short*)qk8;             // 12.6 MB over qk8+vh
  unsigned short* f     = oproj;

  k_prep<<<4864, 256, 0, stream>>>(adj, inx, maskb, x, xb, Wq, Wk, Wv, Wo, W1, W2,
                                   wqkvt, wot, w1t, w2t);
  // G1: [q8|k8|v_f16] = x @ [Wq|Wk|Wv] + b
  k_gemm_qkv<<<768, 256, 0, stream>>>(xb, wqkvt, bq, bk, bv, qk8, vh);
  // quantize v rows (uint8 + per-row scale)
  k_qv<<<2048, 256, 0, stream>>>(vh, v8, vs);
  // attention
  k_attn<<<2048, 256, 0, stream>>>(qk8, v8, vs, maskb, inx, att);
  // G2: oproj = relu(att @ Wo + bo)
  k_gemm<1><<<256, 256, 0, stream>>>(att, wot, bo, oproj, 8192, 512, 512);
  // y = LN(x + oproj)
  k_ln1<<<2048, 256, 0, stream>>>(x, oproj, g1, be1, y);
  // G3: h = relu(y @ W1 + bf1)
  k_gemm<1><<<384, 256, 0, stream>>>(y, w1t, bf1, h, 8192, 768, 512);
  // G4: f = h @ W2 + bf2
  k_gemm<0><<<256, 256, 0, stream>>>(h, w2t, bf2, f, 8192, 512, 768);
  // out = LN(y + f)
  k_ln2<<<2048, 256, 0, stream>>>(y, f, g2, be2, (float*)d_out);
}

// Round 12
// 103.966 us; speedup vs baseline: 1.1293x; 1.1293x over previous
//
#include <hip/hip_runtime.h>
#include <stdint.h>

typedef __attribute__((ext_vector_type(8))) short short8;
typedef __attribute__((ext_vector_type(4))) float f32x4;
typedef __attribute__((ext_vector_type(2))) _Float16 h2;
typedef __attribute__((ext_vector_type(8))) _Float16 half8;

#define QSCALE 21.1666667f    /* 127/6 : q,k,v quantize */
#define VSCALE 0.04724409449f /* 6/127 : v dequant */
#define SCONST 9.86413e-5f    /* (6/127)^2 / sqrt(512) : score dequant */

static __device__ __forceinline__ unsigned short f2bf(float f) {
  unsigned int u = __float_as_uint(f);
  u += 0x7FFFu + ((u >> 16) & 1u);
  return (unsigned short)(u >> 16);
}
static __device__ __forceinline__ float bf2f(unsigned short h) {
  return __uint_as_float(((unsigned int)h) << 16);
}
static __device__ __forceinline__ unsigned short f2h(float f) {
  _Float16 h = (_Float16)f;
  return __builtin_bit_cast(unsigned short, h);
}
static __device__ __forceinline__ signed char q8(float v) {
  float sv = fminf(fmaxf(v * QSCALE, -127.f), 127.f);
  return (signed char)(int)rintf(sv);
}
static __device__ __forceinline__ unsigned char qu8(float v) {
  return (unsigned char)(int)rintf(fminf(fmaxf(v * QSCALE + 128.f, 0.f), 255.f));
}
// LLVM pattern-matches this to v_cvt_f32_ubyteN
static __device__ __forceinline__ float ub(unsigned int x, int n) {
  return (float)((x >> (8 * n)) & 0xffu);
}

#define GLD16(gp, lp) __builtin_amdgcn_global_load_lds( \
    (__attribute__((address_space(1))) void*)(gp), \
    (__attribute__((address_space(3))) void*)(lp), 16, 0, 0)

// --------- fused prep: adj-mask gather | x->f16 | all weight transposes ----
__global__ __launch_bounds__(256) void k_prep(
    const float* __restrict__ adj, const int* __restrict__ inxs,
    float* __restrict__ maskb, const float* __restrict__ x,
    unsigned short* __restrict__ xb,
    const float* __restrict__ Wq, const float* __restrict__ Wk,
    const float* __restrict__ Wv, const float* __restrict__ Wo,
    const float* __restrict__ W1, const float* __restrict__ W2,
    unsigned short* __restrict__ wqkvt, unsigned short* __restrict__ wot,
    unsigned short* __restrict__ w1t, unsigned short* __restrict__ w2t) {
  __shared__ float tile[32][33];
  const int bid = blockIdx.x;
  const int t = threadIdx.x;
  if (bid < 1024) {
    const int xcd = bid & 7;
    const int bb = xcd >> 1;
    const int s = ((bid >> 3) << 1) | (xcd & 1);
    const long row = ((long)bb << 11) | ((long)s << 3) | (t >> 5);
    const int kk = t & 31;
    const int idx = inxs[row * 32 + kk];
    const float a = adj[row * 2048 + idx];
    maskb[row * 32 + kk] = a > 0.f ? 0.f : -1e22f;
    return;
  }
  if (bid < 3072) {
    const int lb = bid - 1024;
    const int xcd = lb & 7;
    const int bb = xcd >> 1;
    const int s = ((lb >> 3) << 1) | (xcd & 1);
    const long row = ((long)bb << 11) | ((long)s << 2) | (t >> 6);
    const int lane = t & 63;
    const float4* p = (const float4*)(x + row * 512 + lane * 8);
    float4 a = p[0], b = p[1];
    short8 v;
    v[0] = (short)f2h(a.x); v[1] = (short)f2h(a.y);
    v[2] = (short)f2h(a.z); v[3] = (short)f2h(a.w);
    v[4] = (short)f2h(b.x); v[5] = (short)f2h(b.y);
    v[6] = (short)f2h(b.z); v[7] = (short)f2h(b.w);
    *(short8*)(xb + row * 512 + lane * 8) = v;
    return;
  }
  const int lb = bid - 3072;
  const float* src;
  unsigned short* dst;
  int R, C, f16, local;
  if (lb < 768) {
    const int m = lb >> 8;
    src = m == 0 ? Wq : (m == 1 ? Wk : Wv);
    dst = wqkvt + (long)m * 512 * 512;
    R = 512; C = 512; f16 = 1; local = lb & 255;
  } else if (lb < 1024) {
    src = Wo; dst = wot; R = 512; C = 512; f16 = 0; local = lb - 768;
  } else if (lb < 1408) {
    src = W1; dst = w1t; R = 512; C = 768; f16 = 0; local = lb - 1024;
  } else {
    src = W2; dst = w2t; R = 768; C = 512; f16 = 0; local = lb - 1408;
  }
  const int ntx = C >> 5;
  const int c0 = (local % ntx) << 5;
  const int r0 = (local / ntx) << 5;
  const int tx = t & 31, ty = t >> 5;
#pragma unroll
  for (int i = 0; i < 4; i++)
    tile[ty + i * 8][tx] = src[(long)(r0 + ty + i * 8) * C + c0 + tx];
  __syncthreads();
#pragma unroll
  for (int i = 0; i < 4; i++) {
    float v = tile[tx][ty + i * 8];
    dst[(long)(c0 + ty + i * 8) * R + r0 + tx] = f16 ? f2h(v) : f2bf(v);
  }
}

// -- G1: f16 MFMA GEMM 128x128, BK=64, dbuf; epilogue -> int8 q,k | uint8 v --
__global__ __launch_bounds__(256) void k_gemm_qkv(
    const unsigned short* __restrict__ A, const unsigned short* __restrict__ Bt,
    const float* __restrict__ bq, const float* __restrict__ bk,
    const float* __restrict__ bv, signed char* __restrict__ qk8,
    unsigned char* __restrict__ v8) {
  const int K = 512;
  __shared__ unsigned short As[2][128 * 64];
  __shared__ unsigned short Bs[2][128 * 64];
  const int t = threadIdx.x;
  const int lane = t & 63;
  const int w = t >> 6;
  const int wr = w >> 1, wc = w & 1;
  const int lin = blockIdx.x;
  const int xcd = lin & 7;
  const int bb = xcd >> 1;
  const int s = ((lin >> 3) << 1) | (xcd & 1);  // 0..191
  const int m0 = (bb * 16 + s / 12) * 128;
  const int n0 = (s % 12) * 128;

  f32x4 acc[4][4];
#pragma unroll
  for (int mi = 0; mi < 4; mi++)
#pragma unroll
    for (int ni = 0; ni < 4; ni++) {
      f32x4 z = {0.f, 0.f, 0.f, 0.f};
      acc[mi][ni] = z;
    }

  auto stage = [&](int buf, int k0) {
#pragma unroll
    for (int i = 0; i < 4; i++) {
      const int c = t + i * 256;
      const int r = c >> 3, j = c & 7;
      GLD16(A + (long)(m0 + r) * K + k0 + ((j ^ (r & 7)) << 3), &As[buf][c * 8]);
    }
#pragma unroll
    for (int i = 0; i < 4; i++) {
      const int c = t + i * 256;
      const int r = c >> 3, j = c & 7;
      GLD16(Bt + (long)(n0 + r) * K + k0 + ((j ^ (r & 7)) << 3), &Bs[buf][c * 8]);
    }
  };

  const int nt = K >> 6;  // 8
  stage(0, 0);
  for (int tt = 0; tt < nt; ++tt) {
    const int cur = tt & 1;
    if (tt + 1 < nt) {
      stage(cur ^ 1, (tt + 1) << 6);
      asm volatile("s_waitcnt vmcnt(8)" ::: "memory");
    } else {
      asm volatile("s_waitcnt vmcnt(0)" ::: "memory");
    }
    __builtin_amdgcn_s_barrier();

#pragma unroll
    for (int kk = 0; kk < 2; kk++) {
      short8 af[4], bf[4];
#pragma unroll
      for (int mi = 0; mi < 4; mi++) {
        const int r = wr * 64 + mi * 16 + (lane & 15);
        const int jj = (kk << 2) + (lane >> 4);
        af[mi] = *(const short8*)&As[cur][r * 64 + ((jj ^ (r & 7)) << 3)];
      }
#pragma unroll
      for (int ni = 0; ni < 4; ni++) {
        const int r = wc * 64 + ni * 16 + (lane & 15);
        const int jj = (kk << 2) + (lane >> 4);
        bf[ni] = *(const short8*)&Bs[cur][r * 64 + ((jj ^ (r & 7)) << 3)];
      }
#pragma unroll
      for (int mi = 0; mi < 4; mi++)
#pragma unroll
        for (int ni = 0; ni < 4; ni++)
          acc[mi][ni] = __builtin_amdgcn_mfma_f32_16x16x32_f16(
              __builtin_bit_cast(half8, af[mi]), __builtin_bit_cast(half8, bf[ni]),
              acc[mi][ni], 0, 0, 0);
    }
    asm volatile("s_waitcnt lgkmcnt(0)" ::: "memory");
    __builtin_amdgcn_s_barrier();
  }

  const int lr = (lane >> 4) * 4;
  const int lc = lane & 15;
  if (n0 < 1024) {  // q,k -> int8
#pragma unroll
    for (int mi = 0; mi < 4; mi++) {
#pragma unroll
      for (int ni = 0; ni < 4; ni++) {
        const int col = n0 + wc * 64 + ni * 16 + lc;
        const float bvv = col < 512 ? bq[col] : bk[col - 512];
#pragma unroll
        for (int r = 0; r < 4; r++) {
          const int row = m0 + wr * 64 + mi * 16 + lr + r;
          qk8[(long)row * 1024 + col] = q8(acc[mi][ni][r] + bvv);
        }
      }
    }
  } else {  // v -> uint8 fixed scale, bias 128
#pragma unroll
    for (int mi = 0; mi < 4; mi++) {
#pragma unroll
      for (int ni = 0; ni < 4; ni++) {
        const int col = n0 + wc * 64 + ni * 16 + lc;
        const float bvv = bv[col - 1024];
#pragma unroll
        for (int r = 0; r < 4; r++) {
          const int row = m0 + wr * 64 + mi * 16 + lr + r;
          v8[(long)row * 512 + (col - 1024)] = qu8(acc[mi][ni][r] + bvv);
        }
      }
    }
  }
}

// ------- bf16 MFMA GEMM, 128x64 tile, BK=64, dbuf + counted vmcnt ---------
// (round-9 proven config: 2-3 blocks/CU)
template <int EPI>
__global__ __launch_bounds__(256) void k_gemm(const unsigned short* __restrict__ A,
                                              const unsigned short* __restrict__ Bt,
                                              const float* __restrict__ bias,
                                              unsigned short* __restrict__ C,
                                              int M, int N, int K) {
  __shared__ unsigned short As[2][128 * 64];
  __shared__ unsigned short Bs[2][64 * 64];
  const int t = threadIdx.x;
  const int lane = t & 63;
  const int w = t >> 6;
  const int wr = w >> 1, wc = w & 1;
  const int lin = blockIdx.x;
  const int xcd = lin & 7;
  const int bb = xcd >> 1;
  const int nx = N >> 6;
  const int s = ((lin >> 3) << 1) | (xcd & 1);
  const int m0 = (bb * 16 + s / nx) * 128;
  const int n0 = (s % nx) * 64;

  f32x4 acc[4][2];
#pragma unroll
  for (int mi = 0; mi < 4; mi++)
#pragma unroll
    for (int ni = 0; ni < 2; ni++) {
      f32x4 z = {0.f, 0.f, 0.f, 0.f};
      acc[mi][ni] = z;
    }

  auto stage = [&](int buf, int k0) {
#pragma unroll
    for (int i = 0; i < 4; i++) {
      const int c = t + i * 256;
      const int r = c >> 3, j = c & 7;
      GLD16(A + (long)(m0 + r) * K + k0 + ((j ^ (r & 7)) << 3), &As[buf][c * 8]);
    }
#pragma unroll
    for (int i = 0; i < 2; i++) {
      const int c = t + i * 256;
      const int r = c >> 3, j = c & 7;
      GLD16(Bt + (long)(n0 + r) * K + k0 + ((j ^ (r & 7)) << 3), &Bs[buf][c * 8]);
    }
  };

  const int nt = K >> 6;
  stage(0, 0);
  for (int tt = 0; tt < nt; ++tt) {
    const int cur = tt & 1;
    if (tt + 1 < nt) {
      stage(cur ^ 1, (tt + 1) << 6);
      asm volatile("s_waitcnt vmcnt(6)" ::: "memory");
    } else {
      asm volatile("s_waitcnt vmcnt(0)" ::: "memory");
    }
    __builtin_amdgcn_s_barrier();

#pragma unroll
    for (int kk = 0; kk < 2; kk++) {
      short8 af[4], bf[2];
#pragma unroll
      for (int mi = 0; mi < 4; mi++) {
        const int r = wr * 64 + mi * 16 + (lane & 15);
        const int jj = (kk << 2) + (lane >> 4);
        af[mi] = *(const short8*)&As[cur][r * 64 + ((jj ^ (r & 7)) << 3)];
      }
#pragma unroll
      for (int ni = 0; ni < 2; ni++) {
        const int r = wc * 32 + ni * 16 + (lane & 15);
        const int jj = (kk << 2) + (lane >> 4);
        bf[ni] = *(const short8*)&Bs[cur][r * 64 + ((jj ^ (r & 7)) << 3)];
      }
#pragma unroll
      for (int mi = 0; mi < 4; mi++)
#pragma unroll
        for (int ni = 0; ni < 2; ni++)
          acc[mi][ni] = __builtin_amdgcn_mfma_f32_16x16x32_bf16(af[mi], bf[ni], acc[mi][ni], 0, 0, 0);
    }
    asm volatile("s_waitcnt lgkmcnt(0)" ::: "memory");
    __builtin_amdgcn_s_barrier();
  }

  const int lr = (lane >> 4) * 4;
  const int lc = lane & 15;
#pragma unroll
  for (int mi = 0; mi < 4; mi++) {
#pragma unroll
    for (int ni = 0; ni < 2; ni++) {
      const int col = n0 + wc * 32 + ni * 16 + lc;
      const float bvv = bias[col];
#pragma unroll
      for (int r = 0; r < 4; r++) {
        const int row = m0 + wr * 64 + mi * 16 + lr + r;
        float v = acc[mi][ni][r] + bvv;
        if (EPI == 1) v = fmaxf(v, 0.f);
        C[(long)row * N + col] = f2bf(v);
      }
    }
  }
}

// ---- attention: int8 q,k scores (sdot4), fixed-scale uint8 v PV -----------
__global__ __launch_bounds__(256, 8) void k_attn(const signed char* __restrict__ qk8,
                                                 const unsigned char* __restrict__ v8,
                                                 const float* __restrict__ maskb,
                                                 const int* __restrict__ inxs,
                                                 unsigned short* __restrict__ att) {
  const int t = threadIdx.x;
  const int lane = t & 63;
  const int w = t >> 6;
  const int bid = blockIdx.x;
  const int xcd = bid & 7;
  const int b = xcd >> 1;
  const int sub = ((bid >> 3) << 1) | (xcd & 1);
  const int row = (b << 11) | (sub << 2) | w;
  const long base = (long)b * 2048;
  const int g = lane >> 4;
  const int li = lane & 15;
  const int kk = lane & 31;

  const int* ix = inxs + (long)row * 32;
  const int ixv = ix[kk];
  const float mval = maskb[(long)row * 32 + kk];

  const uint2* qp = (const uint2*)(qk8 + (long)row * 1024);
  uint2 qc[4];
#pragma unroll
  for (int c = 0; c < 4; c++) qc[c] = qp[li + c * 16];

  // scores: 8 rounds x 4 concurrent neighbors, int8 dot via sdot4
  float scr[8];
#pragma unroll
  for (int r = 0; r < 8; r++) {
    const int nb = __shfl(ixv, r * 4 + g, 64);
    const uint2* kp = (const uint2*)(qk8 + (base + nb) * 1024 + 512);
    int di = 0;
#pragma unroll
    for (int c = 0; c < 4; c++) {
      uint2 kc = kp[li + c * 16];
      di = __builtin_amdgcn_sdot4((int)kc.x, (int)qc[c].x, di, false);
      di = __builtin_amdgcn_sdot4((int)kc.y, (int)qc[c].y, di, false);
    }
#pragma unroll
    for (int m = 1; m <= 8; m <<= 1) di += __shfl_xor(di, m, 64);
    scr[r] = (float)di;
  }

  // redistribute: lane kk takes scr[kk>>2] from lane (kk&3)*16
  const int srcl = (kk & 3) << 4;
  float s = __shfl(scr[0], srcl, 64);
#pragma unroll
  for (int r = 1; r < 8; r++) {
    const float tr = __shfl(scr[r], srcl, 64);
    s = ((kk >> 2) == r) ? tr : s;
  }
  s = s * SCONST + mval;

  // softmax across 32 owned scores
  float mx = s;
#pragma unroll
  for (int d = 1; d <= 16; d <<= 1) mx = fmaxf(mx, __shfl_xor(mx, d, 64));
  const float e = __expf(s - mx);
  float ts = e;
#pragma unroll
  for (int d = 1; d <= 16; d <<= 1) ts += __shfl_xor(ts, d, 64);
  const float inv = 1.f / ts;

  // PV: 32 neighbors, uint8 v rows (8 B/lane), byte-extract unpack.
  // v ≈ VSCALE*(u8 - 128): out_j = VSCALE*(Σ e u8_j)/Σe - 128*VSCALE
  float o[8] = {0, 0, 0, 0, 0, 0, 0, 0};
#pragma unroll
  for (int p = 0; p < 32; p++) {
    const int un = __shfl(ixv, p, 64);
    const float wn = __shfl(e, p, 64);
    const uint2 vv = *(const uint2*)(v8 + (base + un) * 512 + lane * 8);
    o[0] += wn * ub(vv.x, 0);
    o[1] += wn * ub(vv.x, 1);
    o[2] += wn * ub(vv.x, 2);
    o[3] += wn * ub(vv.x, 3);
    o[4] += wn * ub(vv.y, 0);
    o[5] += wn * ub(vv.y, 1);
    o[6] += wn * ub(vv.y, 2);
    o[7] += wn * ub(vv.y, 3);
  }

  short8 ov;
#pragma unroll
  for (int j = 0; j < 8; j++)
    ov[j] = (short)f2bf(VSCALE * (o[j] * inv - 128.f));
  *(short8*)(att + (long)row * 512 + lane * 8) = ov;
}

// ---------------- LN1: y = LN(x_f32 + o_bf16) * g + beta, out bf16 --------
__global__ __launch_bounds__(256) void k_ln1(const float* __restrict__ x,
                                             const unsigned short* __restrict__ o,
                                             const float* __restrict__ g,
                                             const float* __restrict__ beta,
                                             unsigned short* __restrict__ y) {
  const int lane = threadIdx.x & 63;
  const int w = threadIdx.x >> 6;
  const int bid = blockIdx.x;
  const int xcd = bid & 7;
  const int bb = xcd >> 1;
  const int s0 = ((bid >> 3) << 1) | (xcd & 1);
  const long row = ((long)bb << 11) | ((long)s0 << 2) | w;
  const float4* xp = (const float4*)(x + row * 512 + lane * 8);
  float4 x0 = xp[0], x1 = xp[1];
  short8 ov = *(const short8*)(o + row * 512 + lane * 8);
  float tv[8] = {x0.x, x0.y, x0.z, x0.w, x1.x, x1.y, x1.z, x1.w};
  float s = 0.f, s2 = 0.f;
#pragma unroll
  for (int j = 0; j < 8; j++) {
    tv[j] += bf2f((unsigned short)ov[j]);
    s += tv[j];
    s2 += tv[j] * tv[j];
  }
#pragma unroll
  for (int m = 32; m >= 1; m >>= 1) {
    s += __shfl_xor(s, m, 64);
    s2 += __shfl_xor(s2, m, 64);
  }
  const float mean = s * (1.f / 512.f);
  const float var = s2 * (1.f / 512.f) - mean * mean;
  const float r = rsqrtf(var + 1e-5f);
  const float4* gp = (const float4*)(g + lane * 8);
  const float4* bp = (const float4*)(beta + lane * 8);
  float4 g0 = gp[0], g1v = gp[1], b0 = bp[0], b1 = bp[1];
  float gg[8] = {g0.x, g0.y, g0.z, g0.w, g1v.x, g1v.y, g1v.z, g1v.w};
  float bb2[8] = {b0.x, b0.y, b0.z, b0.w, b1.x, b1.y, b1.z, b1.w};
  short8 yv;
#pragma unroll
  for (int j = 0; j < 8; j++) yv[j] = (short)f2bf((tv[j] - mean) * r * gg[j] + bb2[j]);
  *(short8*)(y + row * 512 + lane * 8) = yv;
}

// ---------------- LN2: out_f32 = LN(y_bf16 + f_bf16) * g + beta -----------
__global__ __launch_bounds__(256) void k_ln2(const unsigned short* __restrict__ y,
                                             const unsigned short* __restrict__ f,
                                             const float* __restrict__ g,
                                             const float* __restrict__ beta,
                                             float* __restrict__ out) {
  const int lane = threadIdx.x & 63;
  const int w = threadIdx.x >> 6;
  const int bid = blockIdx.x;
  const int xcd = bid & 7;
  const int bb = xcd >> 1;
  const int s0 = ((bid >> 3) << 1) | (xcd & 1);
  const long row = ((long)bb << 11) | ((long)s0 << 2) | w;
  short8 yv = *(const short8*)(y + row * 512 + lane * 8);
  short8 fv = *(const short8*)(f + row * 512 + lane * 8);
  float tv[8];
  float s = 0.f, s2 = 0.f;
#pragma unroll
  for (int j = 0; j < 8; j++) {
    tv[j] = bf2f((unsigned short)yv[j]) + bf2f((unsigned short)fv[j]);
    s += tv[j];
    s2 += tv[j] * tv[j];
  }
#pragma unroll
  for (int m = 32; m >= 1; m >>= 1) {
    s += __shfl_xor(s, m, 64);
    s2 += __shfl_xor(s2, m, 64);
  }
  const float mean = s * (1.f / 512.f);
  const float var = s2 * (1.f / 512.f) - mean * mean;
  const float r = rsqrtf(var + 1e-5f);
  const float4* gp = (const float4*)(g + lane * 8);
  const float4* bp = (const float4*)(beta + lane * 8);
  float4 g0 = gp[0], g1v = gp[1], b0 = bp[0], b1 = bp[1];
  float gg[8] = {g0.x, g0.y, g0.z, g0.w, g1v.x, g1v.y, g1v.z, g1v.w};
  float bb2[8] = {b0.x, b0.y, b0.z, b0.w, b1.x, b1.y, b1.z, b1.w};
  float ovv[8];
#pragma unroll
  for (int j = 0; j < 8; j++) ovv[j] = (tv[j] - mean) * r * gg[j] + bb2[j];
  float4* op = (float4*)(out + row * 512 + lane * 8);
  float4 o0 = {ovv[0], ovv[1], ovv[2], ovv[3]};
  float4 o1 = {ovv[4], ovv[5], ovv[6], ovv[7]};
  op[0] = o0;
  op[1] = o1;
}

extern "C" void kernel_launch(void* const* d_in, const int* in_sizes, int n_in,
                              void* d_out, int out_size, void* d_ws, size_t ws_size,
                              hipStream_t stream) {
  const float* x   = (const float*)d_in[0];
  const float* adj = (const float*)d_in[1];
  const int*   inx = (const int*)d_in[2];
  const float* Wq  = (const float*)d_in[3];
  const float* bq  = (const float*)d_in[4];
  const float* Wk  = (const float*)d_in[5];
  const float* bk  = (const float*)d_in[6];
  const float* Wv  = (const float*)d_in[7];
  const float* bv  = (const float*)d_in[8];
  const float* Wo  = (const float*)d_in[9];
  const float* bo  = (const float*)d_in[10];
  const float* g1  = (const float*)d_in[11];
  const float* be1 = (const float*)d_in[12];
  const float* W1  = (const float*)d_in[13];
  const float* bf1 = (const float*)d_in[14];
  const float* W2  = (const float*)d_in[15];
  const float* bf2 = (const float*)d_in[16];
  const float* g2  = (const float*)d_in[17];
  const float* be2 = (const float*)d_in[18];

  // workspace (short units). Aliases (stream-ordered safe):
  // att<-xb (dead after G1); h<-qk8+v8 (12,582,912 B == 8192*768*2 B exactly;
  // both dead after attn); f<-oproj (dead after LN1).
  unsigned short* xb    = (unsigned short*)d_ws;            // 4194304 (x f16)
  unsigned short* wqkvt = xb + 4194304;                     // 786432
  unsigned short* wot   = wqkvt + 786432;                   // 262144
  unsigned short* w1t   = wot + 262144;                     // 393216
  unsigned short* w2t   = w1t + 393216;                     // 393216
  signed char*    qk8   = (signed char*)(w2t + 393216);     // 8 MB
  unsigned char*  v8    = (unsigned char*)(qk8 + 8388608);  // 4 MB
  unsigned short* oproj = (unsigned short*)(v8 + 4194304);  // 4194304
  unsigned short* y     = oproj + 4194304;                  // 4194304
  float*          maskb = (float*)(y + 4194304);            // 1 MB
  unsigned short* att   = xb;
  unsigned short* h     = (unsigned short*)qk8;             // exactly fits
  unsigned short* f     = oproj;

  k_prep<<<4864, 256, 0, stream>>>(adj, inx, maskb, x, xb, Wq, Wk, Wv, Wo, W1, W2,
                                   wqkvt, wot, w1t, w2t);
  // G1: [q8|k8|v8] = x @ [Wq|Wk|Wv] + b
  k_gemm_qkv<<<768, 256, 0, stream>>>(xb, wqkvt, bq, bk, bv, qk8, v8);
  // attention
  k_attn<<<2048, 256, 0, stream>>>(qk8, v8, maskb, inx, att);
  // G2: oproj = relu(att @ Wo + bo), 128x64, 512 blocks
  k_gemm<1><<<512, 256, 0, stream>>>(att, wot, bo, oproj, 8192, 512, 512);
  // y = LN(x + oproj)
  k_ln1<<<2048, 256, 0, stream>>>(x, oproj, g1, be1, y);
  // G3: h = relu(y @ W1 + bf1), 768 blocks
  k_gemm<1><<<768, 256, 0, stream>>>(y, w1t, bf1, h, 8192, 768, 512);
  // G4: f = h @ W2 + bf2, 512 blocks
  k_gemm<0><<<512, 256, 0, stream>>>(h, w2t, bf2, f, 8192, 512, 768);
  // out = LN(y + f)
  k_ln2<<<2048, 256, 0, stream>>>(y, f, g2, be2, (float*)d_out);
}

// Round 13
// 100.434 us; speedup vs baseline: 1.1691x; 1.0352x over previous
//
#include <hip/hip_runtime.h>
#include <stdint.h>

typedef __attribute__((ext_vector_type(8))) short short8;
typedef __attribute__((ext_vector_type(4))) float f32x4;
typedef __attribute__((ext_vector_type(8))) _Float16 half8;

#define QSCALE 21.1666667f    /* 127/6 : q,k,v quantize */
#define VSCALE 0.04724409449f /* 6/127 : v dequant */
#define SCONST 9.86413e-5f    /* (6/127)^2 / sqrt(512) : score dequant */

static __device__ __forceinline__ unsigned short f2bf(float f) {
  unsigned int u = __float_as_uint(f);
  u += 0x7FFFu + ((u >> 16) & 1u);
  return (unsigned short)(u >> 16);
}
static __device__ __forceinline__ float bf2f(unsigned short h) {
  return __uint_as_float(((unsigned int)h) << 16);
}
static __device__ __forceinline__ unsigned short f2h(float f) {
  _Float16 h = (_Float16)f;
  return __builtin_bit_cast(unsigned short, h);
}
static __device__ __forceinline__ signed char q8(float v) {
  float sv = fminf(fmaxf(v * QSCALE, -127.f), 127.f);
  return (signed char)(int)rintf(sv);
}
static __device__ __forceinline__ unsigned char qu8(float v) {
  return (unsigned char)(int)rintf(fminf(fmaxf(v * QSCALE + 128.f, 0.f), 255.f));
}
// LLVM pattern-matches this to v_cvt_f32_ubyteN
static __device__ __forceinline__ float ub(unsigned int x, int n) {
  return (float)((x >> (8 * n)) & 0xffu);
}

#define GLD16(gp, lp) __builtin_amdgcn_global_load_lds( \
    (__attribute__((address_space(1))) void*)(gp), \
    (__attribute__((address_space(3))) void*)(lp), 16, 0, 0)

// --------- prep: x->f16 (2048) | Wq/Wk/Wv transposes (768) -----------------
__global__ __launch_bounds__(256) void k_prep(
    const float* __restrict__ x, unsigned short* __restrict__ xb,
    const float* __restrict__ Wq, const float* __restrict__ Wk,
    const float* __restrict__ Wv, unsigned short* __restrict__ wqkvt) {
  __shared__ float tile[32][33];
  const int bid = blockIdx.x;
  const int t = threadIdx.x;
  if (bid < 2048) {
    const int xcd = bid & 7;
    const int bb = xcd >> 1;
    const int s = ((bid >> 3) << 1) | (xcd & 1);
    const long row = ((long)bb << 11) | ((long)s << 2) | (t >> 6);
    const int lane = t & 63;
    const float4* p = (const float4*)(x + row * 512 + lane * 8);
    float4 a = p[0], b = p[1];
    short8 v;
    v[0] = (short)f2h(a.x); v[1] = (short)f2h(a.y);
    v[2] = (short)f2h(a.z); v[3] = (short)f2h(a.w);
    v[4] = (short)f2h(b.x); v[5] = (short)f2h(b.y);
    v[6] = (short)f2h(b.z); v[7] = (short)f2h(b.w);
    *(short8*)(xb + row * 512 + lane * 8) = v;
    return;
  }
  const int lb = bid - 2048;       // 0..767
  const int m = lb >> 8;           // 0,1,2 -> Wq,Wk,Wv
  const float* src = m == 0 ? Wq : (m == 1 ? Wk : Wv);
  unsigned short* dst = wqkvt + (long)m * 512 * 512;
  const int local = lb & 255;
  const int c0 = (local & 15) << 5;
  const int r0 = (local >> 4) << 5;
  const int tx = t & 31, ty = t >> 5;
#pragma unroll
  for (int i = 0; i < 4; i++)
    tile[ty + i * 8][tx] = src[(long)(r0 + ty + i * 8) * 512 + c0 + tx];
  __syncthreads();
#pragma unroll
  for (int i = 0; i < 4; i++)
    dst[(long)(c0 + ty + i * 8) * 512 + r0 + tx] = f2h(tile[tx][ty + i * 8]);
}

// -- G1x: qkv GEMM (768) | adj-mask gather (1024) | Wo/W1/W2 transpose (1024)
// GEMM: f16 MFMA 128x128, BK=64, dbuf; epilogue -> int8 q,k | uint8 v.
// Extra blocks co-schedule under the MFMA-bound gemm blocks (latency-bound
// gather/transpose fill idle issue slots); consumers depend on kernel
// completion, not intra-kernel order.
__global__ __launch_bounds__(256) void k_g1x(
    const unsigned short* __restrict__ A, const unsigned short* __restrict__ Bt,
    const float* __restrict__ bq, const float* __restrict__ bk,
    const float* __restrict__ bv, signed char* __restrict__ qk8,
    unsigned char* __restrict__ v8,
    const float* __restrict__ adj, const int* __restrict__ inxs,
    float* __restrict__ maskb,
    const float* __restrict__ Wo, const float* __restrict__ W1,
    const float* __restrict__ W2, unsigned short* __restrict__ wot,
    unsigned short* __restrict__ w1t, unsigned short* __restrict__ w2t) {
  const int K = 512;
  __shared__ unsigned short As[2][128 * 64];
  __shared__ unsigned short Bs[2][128 * 64];
  const int t = threadIdx.x;
  const int bid = blockIdx.x;

  if (bid >= 768) {
    const int eb = bid - 768;
    if (eb < 1024) {
      // adj-mask gather: 8 rows/block, one lane per (row,kk)
      const int xcd = eb & 7;
      const int bb = xcd >> 1;
      const int s = ((eb >> 3) << 1) | (xcd & 1);
      const long row = ((long)bb << 11) | ((long)s << 3) | (t >> 5);
      const int kk = t & 31;
      const int idx = inxs[row * 32 + kk];
      const float a = adj[row * 2048 + idx];
      maskb[row * 32 + kk] = a > 0.f ? 0.f : -1e22f;
      return;
    }
    // Wo/W1/W2 transpose, fp32 [R][C] -> bf16 [C][R], 32x32 tiles
    float(*tile)[33] = (float(*)[33]) & As[0][0];  // alias gemm LDS
    const int lb = eb - 1024;  // 0..1023
    const float* src;
    unsigned short* dst;
    int R, C, local;
    if (lb < 256) { src = Wo; dst = wot; R = 512; C = 512; local = lb; }
    else if (lb < 640) { src = W1; dst = w1t; R = 512; C = 768; local = lb - 256; }
    else { src = W2; dst = w2t; R = 768; C = 512; local = lb - 640; }
    const int ntx = C >> 5;
    const int c0 = (local % ntx) << 5;
    const int r0 = (local / ntx) << 5;
    const int tx = t & 31, ty = t >> 5;
#pragma unroll
    for (int i = 0; i < 4; i++)
      tile[ty + i * 8][tx] = src[(long)(r0 + ty + i * 8) * C + c0 + tx];
    __syncthreads();
#pragma unroll
    for (int i = 0; i < 4; i++)
      dst[(long)(c0 + ty + i * 8) * R + r0 + tx] = f2bf(tile[tx][ty + i * 8]);
    return;
  }

  // ---------------- GEMM path (bid 0..767) ----------------
  const int lane = t & 63;
  const int w = t >> 6;
  const int wr = w >> 1, wc = w & 1;
  const int xcd = bid & 7;
  const int bb = xcd >> 1;
  const int s = ((bid >> 3) << 1) | (xcd & 1);  // 0..191
  const int m0 = (bb * 16 + s / 12) * 128;
  const int n0 = (s % 12) * 128;

  f32x4 acc[4][4];
#pragma unroll
  for (int mi = 0; mi < 4; mi++)
#pragma unroll
    for (int ni = 0; ni < 4; ni++) {
      f32x4 z = {0.f, 0.f, 0.f, 0.f};
      acc[mi][ni] = z;
    }

  auto stage = [&](int buf, int k0) {
#pragma unroll
    for (int i = 0; i < 4; i++) {
      const int c = t + i * 256;
      const int r = c >> 3, j = c & 7;
      GLD16(A + (long)(m0 + r) * K + k0 + ((j ^ (r & 7)) << 3), &As[buf][c * 8]);
    }
#pragma unroll
    for (int i = 0; i < 4; i++) {
      const int c = t + i * 256;
      const int r = c >> 3, j = c & 7;
      GLD16(Bt + (long)(n0 + r) * K + k0 + ((j ^ (r & 7)) << 3), &Bs[buf][c * 8]);
    }
  };

  const int nt = K >> 6;  // 8
  stage(0, 0);
  for (int tt = 0; tt < nt; ++tt) {
    const int cur = tt & 1;
    if (tt + 1 < nt) {
      stage(cur ^ 1, (tt + 1) << 6);
      asm volatile("s_waitcnt vmcnt(8)" ::: "memory");
    } else {
      asm volatile("s_waitcnt vmcnt(0)" ::: "memory");
    }
    __builtin_amdgcn_s_barrier();

#pragma unroll
    for (int kk = 0; kk < 2; kk++) {
      short8 af[4], bf[4];
#pragma unroll
      for (int mi = 0; mi < 4; mi++) {
        const int r = wr * 64 + mi * 16 + (lane & 15);
        const int jj = (kk << 2) + (lane >> 4);
        af[mi] = *(const short8*)&As[cur][r * 64 + ((jj ^ (r & 7)) << 3)];
      }
#pragma unroll
      for (int ni = 0; ni < 4; ni++) {
        const int r = wc * 64 + ni * 16 + (lane & 15);
        const int jj = (kk << 2) + (lane >> 4);
        bf[ni] = *(const short8*)&Bs[cur][r * 64 + ((jj ^ (r & 7)) << 3)];
      }
#pragma unroll
      for (int mi = 0; mi < 4; mi++)
#pragma unroll
        for (int ni = 0; ni < 4; ni++)
          acc[mi][ni] = __builtin_amdgcn_mfma_f32_16x16x32_f16(
              __builtin_bit_cast(half8, af[mi]), __builtin_bit_cast(half8, bf[ni]),
              acc[mi][ni], 0, 0, 0);
    }
    asm volatile("s_waitcnt lgkmcnt(0)" ::: "memory");
    __builtin_amdgcn_s_barrier();
  }

  const int lr = (lane >> 4) * 4;
  const int lc = lane & 15;
  if (n0 < 1024) {  // q,k -> int8
#pragma unroll
    for (int mi = 0; mi < 4; mi++) {
#pragma unroll
      for (int ni = 0; ni < 4; ni++) {
        const int col = n0 + wc * 64 + ni * 16 + lc;
        const float bvv = col < 512 ? bq[col] : bk[col - 512];
#pragma unroll
        for (int r = 0; r < 4; r++) {
          const int row = m0 + wr * 64 + mi * 16 + lr + r;
          qk8[(long)row * 1024 + col] = q8(acc[mi][ni][r] + bvv);
        }
      }
    }
  } else {  // v -> uint8 fixed scale, bias 128
#pragma unroll
    for (int mi = 0; mi < 4; mi++) {
#pragma unroll
      for (int ni = 0; ni < 4; ni++) {
        const int col = n0 + wc * 64 + ni * 16 + lc;
        const float bvv = bv[col - 1024];
#pragma unroll
        for (int r = 0; r < 4; r++) {
          const int row = m0 + wr * 64 + mi * 16 + lr + r;
          v8[(long)row * 512 + (col - 1024)] = qu8(acc[mi][ni][r] + bvv);
        }
      }
    }
  }
}

// ------- bf16 MFMA GEMM, 128x64 tile, BK=64, dbuf + counted vmcnt ---------
template <int EPI>
__global__ __launch_bounds__(256) void k_gemm(const unsigned short* __restrict__ A,
                                              const unsigned short* __restrict__ Bt,
                                              const float* __restrict__ bias,
                                              unsigned short* __restrict__ C,
                                              int M, int N, int K) {
  __shared__ unsigned short As[2][128 * 64];
  __shared__ unsigned short Bs[2][64 * 64];
  const int t = threadIdx.x;
  const int lane = t & 63;
  const int w = t >> 6;
  const int wr = w >> 1, wc = w & 1;
  const int lin = blockIdx.x;
  const int xcd = lin & 7;
  const int bb = xcd >> 1;
  const int nx = N >> 6;
  const int s = ((lin >> 3) << 1) | (xcd & 1);
  const int m0 = (bb * 16 + s / nx) * 128;
  const int n0 = (s % nx) * 64;

  f32x4 acc[4][2];
#pragma unroll
  for (int mi = 0; mi < 4; mi++)
#pragma unroll
    for (int ni = 0; ni < 2; ni++) {
      f32x4 z = {0.f, 0.f, 0.f, 0.f};
      acc[mi][ni] = z;
    }

  auto stage = [&](int buf, int k0) {
#pragma unroll
    for (int i = 0; i < 4; i++) {
      const int c = t + i * 256;
      const int r = c >> 3, j = c & 7;
      GLD16(A + (long)(m0 + r) * K + k0 + ((j ^ (r & 7)) << 3), &As[buf][c * 8]);
    }
#pragma unroll
    for (int i = 0; i < 2; i++) {
      const int c = t + i * 256;
      const int r = c >> 3, j = c & 7;
      GLD16(Bt + (long)(n0 + r) * K + k0 + ((j ^ (r & 7)) << 3), &Bs[buf][c * 8]);
    }
  };

  const int nt = K >> 6;
  stage(0, 0);
  for (int tt = 0; tt < nt; ++tt) {
    const int cur = tt & 1;
    if (tt + 1 < nt) {
      stage(cur ^ 1, (tt + 1) << 6);
      asm volatile("s_waitcnt vmcnt(6)" ::: "memory");
    } else {
      asm volatile("s_waitcnt vmcnt(0)" ::: "memory");
    }
    __builtin_amdgcn_s_barrier();

#pragma unroll
    for (int kk = 0; kk < 2; kk++) {
      short8 af[4], bf[2];
#pragma unroll
      for (int mi = 0; mi < 4; mi++) {
        const int r = wr * 64 + mi * 16 + (lane & 15);
        const int jj = (kk << 2) + (lane >> 4);
        af[mi] = *(const short8*)&As[cur][r * 64 + ((jj ^ (r & 7)) << 3)];
      }
#pragma unroll
      for (int ni = 0; ni < 2; ni++) {
        const int r = wc * 32 + ni * 16 + (lane & 15);
        const int jj = (kk << 2) + (lane >> 4);
        bf[ni] = *(const short8*)&Bs[cur][r * 64 + ((jj ^ (r & 7)) << 3)];
      }
#pragma unroll
      for (int mi = 0; mi < 4; mi++)
#pragma unroll
        for (int ni = 0; ni < 2; ni++)
          acc[mi][ni] = __builtin_amdgcn_mfma_f32_16x16x32_bf16(af[mi], bf[ni], acc[mi][ni], 0, 0, 0);
    }
    asm volatile("s_waitcnt lgkmcnt(0)" ::: "memory");
    __builtin_amdgcn_s_barrier();
  }

  const int lr = (lane >> 4) * 4;
  const int lc = lane & 15;
#pragma unroll
  for (int mi = 0; mi < 4; mi++) {
#pragma unroll
    for (int ni = 0; ni < 2; ni++) {
      const int col = n0 + wc * 32 + ni * 16 + lc;
      const float bvv = bias[col];
#pragma unroll
      for (int r = 0; r < 4; r++) {
        const int row = m0 + wr * 64 + mi * 16 + lr + r;
        float v = acc[mi][ni][r] + bvv;
        if (EPI == 1) v = fmaxf(v, 0.f);
        C[(long)row * N + col] = f2bf(v);
      }
    }
  }
}

// ---- attention: int8 q,k scores (sdot4, uint4 loads), uint8 v PV ----------
__global__ __launch_bounds__(256, 8) void k_attn(const signed char* __restrict__ qk8,
                                                 const unsigned char* __restrict__ v8,
                                                 const float* __restrict__ maskb,
                                                 const int* __restrict__ inxs,
                                                 unsigned short* __restrict__ att) {
  const int t = threadIdx.x;
  const int lane = t & 63;
  const int w = t >> 6;
  const int bid = blockIdx.x;
  const int xcd = bid & 7;
  const int b = xcd >> 1;
  const int sub = ((bid >> 3) << 1) | (xcd & 1);
  const int row = (b << 11) | (sub << 2) | w;
  const long base = (long)b * 2048;
  const int g = lane >> 4;
  const int li = lane & 15;
  const int kk = lane & 31;

  const int* ix = inxs + (long)row * 32;
  const int ixv = ix[kk];
  const float mval = maskb[(long)row * 32 + kk];

  // q row = 512B = 32 uint4 chunks; lane li covers {li, li+16}
  const uint4* qp = (const uint4*)(qk8 + (long)row * 1024);
  uint4 qc[2];
#pragma unroll
  for (int c = 0; c < 2; c++) qc[c] = qp[li + c * 16];

  // scores: 8 rounds x 4 concurrent neighbors; 2 uint4 loads + 8 sdot4/round
  float scr[8];
#pragma unroll
  for (int r = 0; r < 8; r++) {
    const int nb = __shfl(ixv, r * 4 + g, 64);
    const uint4* kp = (const uint4*)(qk8 + (base + nb) * 1024 + 512);
    int di = 0;
#pragma unroll
    for (int c = 0; c < 2; c++) {
      const uint4 kc = kp[li + c * 16];
      di = __builtin_amdgcn_sdot4((int)kc.x, (int)qc[c].x, di, false);
      di = __builtin_amdgcn_sdot4((int)kc.y, (int)qc[c].y, di, false);
      di = __builtin_amdgcn_sdot4((int)kc.z, (int)qc[c].z, di, false);
      di = __builtin_amdgcn_sdot4((int)kc.w, (int)qc[c].w, di, false);
    }
#pragma unroll
    for (int m = 1; m <= 8; m <<= 1) di += __shfl_xor(di, m, 64);
    scr[r] = (float)di;
  }

  // redistribute: lane kk takes scr[kk>>2] from lane (kk&3)*16
  const int srcl = (kk & 3) << 4;
  float s = __shfl(scr[0], srcl, 64);
#pragma unroll
  for (int r = 1; r < 8; r++) {
    const float tr = __shfl(scr[r], srcl, 64);
    s = ((kk >> 2) == r) ? tr : s;
  }
  s = s * SCONST + mval;

  // softmax across 32 owned scores
  float mx = s;
#pragma unroll
  for (int d = 1; d <= 16; d <<= 1) mx = fmaxf(mx, __shfl_xor(mx, d, 64));
  const float e = __expf(s - mx);
  float ts = e;
#pragma unroll
  for (int d = 1; d <= 16; d <<= 1) ts += __shfl_xor(ts, d, 64);
  const float inv = 1.f / ts;

  // PV: 32 neighbors, uint8 v rows (8 B/lane), byte-extract unpack.
  // v ≈ VSCALE*(u8 - 128): out_j = VSCALE*((Σ e u8_j)/Σe - 128)
  float o[8] = {0, 0, 0, 0, 0, 0, 0, 0};
#pragma unroll
  for (int p = 0; p < 32; p++) {
    const int un = __shfl(ixv, p, 64);
    const float wn = __shfl(e, p, 64);
    const uint2 vv = *(const uint2*)(v8 + (base + un) * 512 + lane * 8);
    o[0] += wn * ub(vv.x, 0);
    o[1] += wn * ub(vv.x, 1);
    o[2] += wn * ub(vv.x, 2);
    o[3] += wn * ub(vv.x, 3);
    o[4] += wn * ub(vv.y, 0);
    o[5] += wn * ub(vv.y, 1);
    o[6] += wn * ub(vv.y, 2);
    o[7] += wn * ub(vv.y, 3);
  }

  short8 ov;
#pragma unroll
  for (int j = 0; j < 8; j++)
    ov[j] = (short)f2bf(VSCALE * (o[j] * inv - 128.f));
  *(short8*)(att + (long)row * 512 + lane * 8) = ov;
}

// ---------------- LN1: y = LN(x_f32 + o_bf16) * g + beta, out bf16 --------
__global__ __launch_bounds__(256) void k_ln1(const float* __restrict__ x,
                                             const unsigned short* __restrict__ o,
                                             const float* __restrict__ g,
                                             const float* __restrict__ beta,
                                             unsigned short* __restrict__ y) {
  const int lane = threadIdx.x & 63;
  const int w = threadIdx.x >> 6;
  const int bid = blockIdx.x;
  const int xcd = bid & 7;
  const int bb = xcd >> 1;
  const int s0 = ((bid >> 3) << 1) | (xcd & 1);
  const long row = ((long)bb << 11) | ((long)s0 << 2) | w;
  const float4* xp = (const float4*)(x + row * 512 + lane * 8);
  float4 x0 = xp[0], x1 = xp[1];
  short8 ov = *(const short8*)(o + row * 512 + lane * 8);
  float tv[8] = {x0.x, x0.y, x0.z, x0.w, x1.x, x1.y, x1.z, x1.w};
  float s = 0.f, s2 = 0.f;
#pragma unroll
  for (int j = 0; j < 8; j++) {
    tv[j] += bf2f((unsigned short)ov[j]);
    s += tv[j];
    s2 += tv[j] * tv[j];
  }
#pragma unroll
  for (int m = 32; m >= 1; m >>= 1) {
    s += __shfl_xor(s, m, 64);
    s2 += __shfl_xor(s2, m, 64);
  }
  const float mean = s * (1.f / 512.f);
  const float var = s2 * (1.f / 512.f) - mean * mean;
  const float r = rsqrtf(var + 1e-5f);
  const float4* gp = (const float4*)(g + lane * 8);
  const float4* bp = (const float4*)(beta + lane * 8);
  float4 g0 = gp[0], g1v = gp[1], b0 = bp[0], b1 = bp[1];
  float gg[8] = {g0.x, g0.y, g0.z, g0.w, g1v.x, g1v.y, g1v.z, g1v.w};
  float bb2[8] = {b0.x, b0.y, b0.z, b0.w, b1.x, b1.y, b1.z, b1.w};
  short8 yv;
#pragma unroll
  for (int j = 0; j < 8; j++) yv[j] = (short)f2bf((tv[j] - mean) * r * gg[j] + bb2[j]);
  *(short8*)(y + row * 512 + lane * 8) = yv;
}

// ---------------- LN2: out_f32 = LN(y_bf16 + f_bf16) * g + beta -----------
__global__ __launch_bounds__(256) void k_ln2(const unsigned short* __restrict__ y,
                                             const unsigned short* __restrict__ f,
                                             const float* __restrict__ g,
                                             const float* __restrict__ beta,
                                             float* __restrict__ out) {
  const int lane = threadIdx.x & 63;
  const int w = threadIdx.x >> 6;
  const int bid = blockIdx.x;
  const int xcd = bid & 7;
  const int bb = xcd >> 1;
  const int s0 = ((bid >> 3) << 1) | (xcd & 1);
  const long row = ((long)bb << 11) | ((long)s0 << 2) | w;
  short8 yv = *(const short8*)(y + row * 512 + lane * 8);
  short8 fv = *(const short8*)(f + row * 512 + lane * 8);
  float tv[8];
  float s = 0.f, s2 = 0.f;
#pragma unroll
  for (int j = 0; j < 8; j++) {
    tv[j] = bf2f((unsigned short)yv[j]) + bf2f((unsigned short)fv[j]);
    s += tv[j];
    s2 += tv[j] * tv[j];
  }
#pragma unroll
  for (int m = 32; m >= 1; m >>= 1) {
    s += __shfl_xor(s, m, 64);
    s2 += __shfl_xor(s2, m, 64);
  }
  const float mean = s * (1.f / 512.f);
  const float var = s2 * (1.f / 512.f) - mean * mean;
  const float r = rsqrtf(var + 1e-5f);
  const float4* gp = (const float4*)(g + lane * 8);
  const float4* bp = (const float4*)(beta + lane * 8);
  float4 g0 = gp[0], g1v = gp[1], b0 = bp[0], b1 = bp[1];
  float gg[8] = {g0.x, g0.y, g0.z, g0.w, g1v.x, g1v.y, g1v.z, g1v.w};
  float bb2[8] = {b0.x, b0.y, b0.z, b0.w, b1.x, b1.y, b1.z, b1.w};
  float ovv[8];
#pragma unroll
  for (int j = 0; j < 8; j++) ovv[j] = (tv[j] - mean) * r * gg[j] + bb2[j];
  float4* op = (float4*)(out + row * 512 + lane * 8);
  float4 o0 = {ovv[0], ovv[1], ovv[2], ovv[3]};
  float4 o1 = {ovv[4], ovv[5], ovv[6], ovv[7]};
  op[0] = o0;
  op[1] = o1;
}

extern "C" void kernel_launch(void* const* d_in, const int* in_sizes, int n_in,
                              void* d_out, int out_size, void* d_ws, size_t ws_size,
                              hipStream_t stream) {
  const float* x   = (const float*)d_in[0];
  const float* adj = (const float*)d_in[1];
  const int*   inx = (const int*)d_in[2];
  const float* Wq  = (const float*)d_in[3];
  const float* bq  = (const float*)d_in[4];
  const float* Wk  = (const float*)d_in[5];
  const float* bk  = (const float*)d_in[6];
  const float* Wv  = (const float*)d_in[7];
  const float* bv  = (const float*)d_in[8];
  const float* Wo  = (const float*)d_in[9];
  const float* bo  = (const float*)d_in[10];
  const float* g1  = (const float*)d_in[11];
  const float* be1 = (const float*)d_in[12];
  const float* W1  = (const float*)d_in[13];
  const float* bf1 = (const float*)d_in[14];
  const float* W2  = (const float*)d_in[15];
  const float* bf2 = (const float*)d_in[16];
  const float* g2  = (const float*)d_in[17];
  const float* be2 = (const float*)d_in[18];

  // workspace (short units). Aliases (stream-ordered safe):
  // att<-xb (dead after G1x); h<-qk8+v8 (12,582,912 B == 8192*768*2 B exactly;
  // both dead after attn); f<-oproj (dead after LN1).
  unsigned short* xb    = (unsigned short*)d_ws;            // 4194304 (x f16)
  unsigned short* wqkvt = xb + 4194304;                     // 786432
  unsigned short* wot   = wqkvt + 786432;                   // 262144
  unsigned short* w1t   = wot + 262144;                     // 393216
  unsigned short* w2t   = w1t + 393216;                     // 393216
  signed char*    qk8   = (signed char*)(w2t + 393216);     // 8 MB
  unsigned char*  v8    = (unsigned char*)(qk8 + 8388608);  // 4 MB
  unsigned short* oproj = (unsigned short*)(v8 + 4194304);  // 4194304
  unsigned short* y     = oproj + 4194304;                  // 4194304
  float*          maskb = (float*)(y + 4194304);            // 1 MB
  unsigned short* att   = xb;
  unsigned short* h     = (unsigned short*)qk8;             // exactly fits
  unsigned short* f     = oproj;

  // prep: x->f16 + Wq/Wk/Wv transposes (only what G1x needs)
  k_prep<<<2816, 256, 0, stream>>>(x, xb, Wq, Wk, Wv, wqkvt);
  // G1x: qkv GEMM + (overlapped) adj-mask gather + Wo/W1/W2 transposes
  k_g1x<<<2816, 256, 0, stream>>>(xb, wqkvt, bq, bk, bv, qk8, v8,
                                  adj, inx, maskb, Wo, W1, W2, wot, w1t, w2t);
  // attention
  k_attn<<<2048, 256, 0, stream>>>(qk8, v8, maskb, inx, att);
  // G2: oproj = relu(att @ Wo + bo)
  k_gemm<1><<<512, 256, 0, stream>>>(att, wot, bo, oproj, 8192, 512, 512);
  // y = LN(x + oproj)
  k_ln1<<<2048, 256, 0, stream>>>(x, oproj, g1, be1, y);
  // G3: h = relu(y @ W1 + bf1)
  k_gemm<1><<<768, 256, 0, stream>>>(y, w1t, bf1, h, 8192, 768, 512);
  // G4: f = h @ W2 + bf2
  k_gemm<0><<<512, 256, 0, stream>>>(h, w2t, bf2, f, 8192, 512, 768);
  // out = LN(y + f)
  k_ln2<<<2048, 256, 0, stream>>>(y, f, g2, be2, (float*)d_out);
}